// Round 1
// baseline (723.525 us; speedup 1.0000x reference)
//
#include <hip/hip_runtime.h>
#include <math.h>

static constexpr int B_  = 2;
static constexpr int S_  = 2048;
static constexpr int E_  = 1024;
static constexpr int NH_ = 4;
static constexpr int HD_ = 256;
static constexpr int BH_ = B_ * NH_;
static constexpr int TM  = 16;   // rows per tile
static constexpr int TN  = 32;   // cols per tile

// ---------------- Kernel A: gate projections ----------------
// grid: B*S blocks, 256 threads. ig/fg laid out (B,NH,S).
__global__ __launch_bounds__(256) void gates_kernel(
    const float* __restrict__ q, const float* __restrict__ k, const float* __restrict__ v,
    const float* __restrict__ igk, const float* __restrict__ igb,
    const float* __restrict__ fgk, const float* __restrict__ fgb,
    float* __restrict__ ig_out, float* __restrict__ fg_out)
{
    const int bs = blockIdx.x;            // b*S + s
    const int b = bs >> 11, s = bs & (S_ - 1);
    const int t = threadIdx.x;
    const float* qrow = q + (size_t)bs * E_;
    const float* krow = k + (size_t)bs * E_;
    const float* vrow = v + (size_t)bs * E_;
    float accI[4] = {0.f,0.f,0.f,0.f}, accF[4] = {0.f,0.f,0.f,0.f};
    #pragma unroll
    for (int u = 0; u < 12; ++u) {
        int e = t + 256 * u;
        float g;
        if (e < E_)            g = qrow[e];
        else if (e < 2 * E_)   g = krow[e - E_];
        else                   g = vrow[e - 2 * E_];
        float4 wi = ((const float4*)igk)[e];
        float4 wf = ((const float4*)fgk)[e];
        accI[0] = fmaf(g, wi.x, accI[0]); accI[1] = fmaf(g, wi.y, accI[1]);
        accI[2] = fmaf(g, wi.z, accI[2]); accI[3] = fmaf(g, wi.w, accI[3]);
        accF[0] = fmaf(g, wf.x, accF[0]); accF[1] = fmaf(g, wf.y, accF[1]);
        accF[2] = fmaf(g, wf.z, accF[2]); accF[3] = fmaf(g, wf.w, accF[3]);
    }
    #pragma unroll
    for (int m = 1; m < 64; m <<= 1) {
        #pragma unroll
        for (int h = 0; h < 4; ++h) {
            accI[h] += __shfl_xor(accI[h], m);
            accF[h] += __shfl_xor(accF[h], m);
        }
    }
    __shared__ float ws[4][8];
    const int wave = t >> 6;
    if ((t & 63) == 0) {
        #pragma unroll
        for (int h = 0; h < 4; ++h) { ws[wave][h] = accI[h]; ws[wave][4 + h] = accF[h]; }
    }
    __syncthreads();
    if (t < 8) {
        float tot = ws[0][t] + ws[1][t] + ws[2][t] + ws[3][t];
        int h = t & 3;
        if (t < 4) ig_out[((size_t)(b * NH_ + h)) * S_ + s] = tot + igb[h];
        else       fg_out[((size_t)(b * NH_ + h)) * S_ + s] = tot + fgb[h];
    }
}

// ---------------- Kernel B: log-sigmoid cumsum + cummax ----------------
// grid: BH blocks, 256 threads; thread t owns s = t*8 .. t*8+7.
// Outputs per (b,h,s): AmM = A - M (<=0), G = ig - A, M.
__global__ __launch_bounds__(256) void scan_kernel(
    const float* __restrict__ ig, const float* __restrict__ fg,
    float* __restrict__ AmM, float* __restrict__ G, float* __restrict__ M)
{
    const int bh = blockIdx.x;
    const int t = threadIdx.x;
    const float* fgp = fg + (size_t)bh * S_;
    const float* igp = ig + (size_t)bh * S_;
    float ls[8];
    float run = 0.f;
    #pragma unroll
    for (int i = 0; i < 8; ++i) {
        float x = fgp[t * 8 + i];
        // stable log_sigmoid
        float l = (x >= 0.f) ? -log1pf(expf(-x)) : (x - log1pf(expf(x)));
        run += l;
        ls[i] = run;
    }
    __shared__ float sc[256];
    sc[t] = run;
    __syncthreads();
    for (int off = 1; off < 256; off <<= 1) {
        float vv = (t >= off) ? sc[t - off] : 0.f;
        __syncthreads();
        sc[t] += vv;
        __syncthreads();
    }
    float excl = sc[t] - run;
    float A[8], g[8], gm[8];
    #pragma unroll
    for (int i = 0; i < 8; ++i) A[i] = excl + ls[i];
    float rmax = -__builtin_inff();
    #pragma unroll
    for (int i = 0; i < 8; ++i) {
        g[i] = igp[t * 8 + i] - A[i];
        rmax = fmaxf(rmax, g[i]);
        gm[i] = rmax;   // local inclusive cummax
    }
    __syncthreads();           // everyone done reading sc from pass 1
    sc[t] = rmax;
    __syncthreads();
    for (int off = 1; off < 256; off <<= 1) {
        float vv = (t >= off) ? sc[t - off] : -__builtin_inff();
        __syncthreads();
        sc[t] = fmaxf(sc[t], vv);
        __syncthreads();
    }
    float exm = (t == 0) ? -__builtin_inff() : sc[t - 1];
    #pragma unroll
    for (int i = 0; i < 8; ++i) {
        float cm = fmaxf(exm, gm[i]);
        float Mi = A[i] + cm;
        size_t idx = (size_t)bh * S_ + t * 8 + i;
        AmM[idx] = A[i] - Mi;
        G[idx]   = g[i];
        M[idx]   = Mi;
    }
}

// ---------------- Kernel C: causal decay attention + fused RMSNorm ----------------
// grid: BH*64 blocks; block z handles (bh = z>>6) row-tiles {u, 127-u} (u = z&63)
// so every block performs ~65 column-tile units (uniform work).
__global__ __launch_bounds__(256, 2) void mlstm_kernel(
    const float* __restrict__ q, const float* __restrict__ k, const float* __restrict__ v,
    const float* __restrict__ AmM, const float* __restrict__ G, const float* __restrict__ Mr,
    const float* __restrict__ rms_scale, float* __restrict__ out)
{
    __shared__ __align__(16) float Qs[TM][HD_];        // 16 KB
    __shared__ __align__(16) float Ks[TN][HD_ + 4];    // 33.3 KB, stride 260 floats
    __shared__ __align__(16) float Ps[TN][TM + 4];     // P^T: [col][row], stride 20
    __shared__ float rowsum[TM];
    __shared__ float rowAmM[TM];
    __shared__ float rowM[TM];

    const int z  = blockIdx.x;
    const int bh = z >> 6;
    const int u  = z & 63;
    const int b  = bh >> 2, h = bh & 3;
    const int t  = threadIdx.x;

    const float* qb = q + ((size_t)b * S_) * E_ + h * HD_;
    const float* kb = k + ((size_t)b * S_) * E_ + h * HD_;
    const float* vb = v + ((size_t)b * S_) * E_ + h * HD_;
    const float* AmMp = AmM + (size_t)bh * S_;
    const float* Gp   = G   + (size_t)bh * S_;
    const float* Mp   = Mr  + (size_t)bh * S_;

    // phase-1 mapping
    const int c  = t & 31;        // KV column within tile
    const int r2 = t >> 5;        // rows r2 and r2+8
    // phase-2 mapping
    const int rg = t >> 6;        // wave id -> rows rg*4 .. rg*4+3
    const int cg = t & 63;        // cols cg*4 .. cg*4+3
    const float4 rsc = ((const float4*)rms_scale)[cg];

    for (int pass = 0; pass < 2; ++pass) {
        const int rt   = (pass == 0) ? u : (127 - u);
        const int row0 = rt * TM;
        __syncthreads();   // protect LDS reuse from previous pass epilogue
        // stage Q tile (16x256), coalesced float4
        for (int p = t; p < TM * HD_ / 4; p += 256) {
            int r = p >> 6, kq = p & 63;
            float4 qv = ((const float4*)(qb + (size_t)(row0 + r) * E_))[kq];
            ((float4*)&Qs[r][0])[kq] = qv;
        }
        if (t < TM) {
            rowAmM[t] = AmMp[row0 + t];
            rowM[t]   = Mp[row0 + t];
            rowsum[t] = 0.f;
        }
        float4 acc4[4];
        #pragma unroll
        for (int i = 0; i < 4; ++i) acc4[i] = make_float4(0.f, 0.f, 0.f, 0.f);

        const int jt_max = (row0 + TM - 1) >> 5;
        __syncthreads();

        for (int jt = 0; jt <= jt_max; ++jt) {
            const int col0 = jt * TN;
            // stage K tile (32x256), coalesced float4, padded rows
            for (int p = t; p < TN * HD_ / 4; p += 256) {
                int r = p >> 6, kq = p & 63;
                float4 kv = ((const float4*)(kb + (size_t)(col0 + r) * E_))[kq];
                ((float4*)&Ks[r][0])[kq] = kv;
            }
            __syncthreads();
            // ---- phase 1: S = Q K^T, scale + decay + mask -> Ps, rowsum ----
            float s0 = 0.f, s1 = 0.f;
            const float4* qr0 = (const float4*)&Qs[r2][0];
            const float4* qr1 = (const float4*)&Qs[r2 + 8][0];
            const float4* kr  = (const float4*)&Ks[c][0];
            #pragma unroll 8
            for (int kk = 0; kk < HD_ / 4; ++kk) {
                float4 kv = kr[kk];
                float4 q0 = qr0[kk];
                float4 q1 = qr1[kk];
                s0 = fmaf(q0.x, kv.x, s0); s0 = fmaf(q0.y, kv.y, s0);
                s0 = fmaf(q0.z, kv.z, s0); s0 = fmaf(q0.w, kv.w, s0);
                s1 = fmaf(q1.x, kv.x, s1); s1 = fmaf(q1.y, kv.y, s1);
                s1 = fmaf(q1.z, kv.z, s1); s1 = fmaf(q1.w, kv.w, s1);
            }
            const int gcol = col0 + c;
            const float gcv = Gp[gcol];
            const int gr0 = row0 + r2, gr1 = row0 + r2 + 8;
            // exp(A[i]-M[i] + G[j]) must stay fused in ONE exp (A,G ~ +-200 separately)
            float p0 = (gcol <= gr0) ? s0 * 0.0625f * __expf(rowAmM[r2] + gcv) : 0.f;
            float p1 = (gcol <= gr1) ? s1 * 0.0625f * __expf(rowAmM[r2 + 8] + gcv) : 0.f;
            Ps[c][r2]     = p0;
            Ps[c][r2 + 8] = p1;
            float t0 = p0, t1 = p1;
            #pragma unroll
            for (int m = 1; m < 32; m <<= 1) { t0 += __shfl_xor(t0, m); t1 += __shfl_xor(t1, m); }
            if (c == 0) { rowsum[r2] += t0; rowsum[r2 + 8] += t1; }
            __syncthreads();
            // ---- phase 2: acc += P @ V  (V straight from global, coalesced) ----
            const float* vptr = vb + (size_t)col0 * E_ + cg * 4;
            #pragma unroll 4
            for (int j = 0; j < TN; ++j) {
                float4 vj = *(const float4*)(vptr);
                vptr += E_;
                float4 pj = *(const float4*)&Ps[j][rg * 4];   // rows rg*4..+3, broadcast
                acc4[0].x = fmaf(pj.x, vj.x, acc4[0].x); acc4[0].y = fmaf(pj.x, vj.y, acc4[0].y);
                acc4[0].z = fmaf(pj.x, vj.z, acc4[0].z); acc4[0].w = fmaf(pj.x, vj.w, acc4[0].w);
                acc4[1].x = fmaf(pj.y, vj.x, acc4[1].x); acc4[1].y = fmaf(pj.y, vj.y, acc4[1].y);
                acc4[1].z = fmaf(pj.y, vj.z, acc4[1].z); acc4[1].w = fmaf(pj.y, vj.w, acc4[1].w);
                acc4[2].x = fmaf(pj.z, vj.x, acc4[2].x); acc4[2].y = fmaf(pj.z, vj.y, acc4[2].y);
                acc4[2].z = fmaf(pj.z, vj.z, acc4[2].z); acc4[2].w = fmaf(pj.z, vj.w, acc4[2].w);
                acc4[3].x = fmaf(pj.w, vj.x, acc4[3].x); acc4[3].y = fmaf(pj.w, vj.y, acc4[3].y);
                acc4[3].z = fmaf(pj.w, vj.z, acc4[3].z); acc4[3].w = fmaf(pj.w, vj.w, acc4[3].w);
            }
            __syncthreads();
        }
        // ---- epilogue: normalize by n, fused RMSNorm, write ----
        #pragma unroll
        for (int i = 0; i < 4; ++i) {
            const int r = rg * 4 + i;
            float n = fmaxf(rowsum[r], __expf(-rowM[r])) + 1e-6f;
            float inv = 1.0f / n;
            float4 hv;
            hv.x = acc4[i].x * inv; hv.y = acc4[i].y * inv;
            hv.z = acc4[i].z * inv; hv.w = acc4[i].w * inv;
            float ss = hv.x * hv.x + hv.y * hv.y + hv.z * hv.z + hv.w * hv.w;
            #pragma unroll
            for (int m = 1; m < 64; m <<= 1) ss += __shfl_xor(ss, m);
            float rstd = rsqrtf(ss * (1.0f / HD_) + 1e-6f);
            float4 ov;
            ov.x = hv.x * rstd * (1.f + rsc.x);
            ov.y = hv.y * rstd * (1.f + rsc.y);
            ov.z = hv.z * rstd * (1.f + rsc.z);
            ov.w = hv.w * rstd * (1.f + rsc.w);
            *(float4*)(out + ((size_t)(b * S_ + row0 + r)) * E_ + h * HD_ + cg * 4) = ov;
        }
    }
}

extern "C" void kernel_launch(void* const* d_in, const int* in_sizes, int n_in,
                              void* d_out, int out_size, void* d_ws, size_t ws_size,
                              hipStream_t stream) {
    (void)in_sizes; (void)n_in; (void)out_size; (void)ws_size;
    const float* q   = (const float*)d_in[0];
    const float* k   = (const float*)d_in[1];
    const float* v   = (const float*)d_in[2];
    const float* igk = (const float*)d_in[3];
    const float* igb = (const float*)d_in[4];
    const float* fgk = (const float*)d_in[5];
    const float* fgb = (const float*)d_in[6];
    const float* rsc = (const float*)d_in[7];
    float* out = (float*)d_out;

    float* ws  = (float*)d_ws;
    float* ig  = ws;                    // BH*S
    float* fg  = ws + (size_t)BH_ * S_;
    float* AmM = ws + (size_t)2 * BH_ * S_;
    float* G   = ws + (size_t)3 * BH_ * S_;
    float* M   = ws + (size_t)4 * BH_ * S_;

    gates_kernel<<<B_ * S_, 256, 0, stream>>>(q, k, v, igk, igb, fgk, fgb, ig, fg);
    scan_kernel<<<BH_, 256, 0, stream>>>(ig, fg, AmM, G, M);
    mlstm_kernel<<<BH_ * 64, 256, 0, stream>>>(q, k, v, AmM, G, M, rsc, out);
}

// Round 3
// 249.484 us; speedup vs baseline: 2.9001x; 2.9001x over previous
//
#include <hip/hip_runtime.h>
#include <math.h>

static constexpr int B_  = 2;
static constexpr int S_  = 2048;
static constexpr int E_  = 1024;
static constexpr int NH_ = 4;
static constexpr int HD_ = 256;
static constexpr int BH_ = B_ * NH_;

typedef __attribute__((ext_vector_type(8))) _Float16 half8;
typedef __attribute__((ext_vector_type(4))) float    f32x4;
typedef __attribute__((ext_vector_type(4))) _Float16 half4v;

// ---------------- Kernel A: gate projections + fp16 convert of Q(/16), K ----------------
__global__ __launch_bounds__(256) void gates_kernel(
    const float* __restrict__ q, const float* __restrict__ k, const float* __restrict__ v,
    const float* __restrict__ igk, const float* __restrict__ igb,
    const float* __restrict__ fgk, const float* __restrict__ fgb,
    float* __restrict__ ig_out, float* __restrict__ fg_out,
    _Float16* __restrict__ Qh, _Float16* __restrict__ Kh)
{
    const int bs = blockIdx.x;            // b*S + s
    const int b = bs >> 11, s = bs & (S_ - 1);
    const int t = threadIdx.x;
    const float* qrow = q + (size_t)bs * E_;
    const float* krow = k + (size_t)bs * E_;
    const float* vrow = v + (size_t)bs * E_;
    float accI[4] = {0.f,0.f,0.f,0.f}, accF[4] = {0.f,0.f,0.f,0.f};
    #pragma unroll
    for (int u = 0; u < 12; ++u) {
        int e = t + 256 * u;
        float g;
        if (u < 4)       g = qrow[e];
        else if (u < 8)  g = krow[e - E_];
        else             g = vrow[e - 2 * E_];
        if (u < 4) {
            int hh = e >> 8, d = e & 255;
            Qh[(((size_t)(b * NH_ + hh)) * S_ + s) * HD_ + d] = (_Float16)(g * 0.0625f);
        } else if (u < 8) {
            int e2 = e - E_; int hh = e2 >> 8, d = e2 & 255;
            Kh[(((size_t)(b * NH_ + hh)) * S_ + s) * HD_ + d] = (_Float16)g;
        }
        float4 wi = ((const float4*)igk)[e];
        float4 wf = ((const float4*)fgk)[e];
        accI[0] = fmaf(g, wi.x, accI[0]); accI[1] = fmaf(g, wi.y, accI[1]);
        accI[2] = fmaf(g, wi.z, accI[2]); accI[3] = fmaf(g, wi.w, accI[3]);
        accF[0] = fmaf(g, wf.x, accF[0]); accF[1] = fmaf(g, wf.y, accF[1]);
        accF[2] = fmaf(g, wf.z, accF[2]); accF[3] = fmaf(g, wf.w, accF[3]);
    }
    #pragma unroll
    for (int m = 1; m < 64; m <<= 1) {
        #pragma unroll
        for (int h = 0; h < 4; ++h) {
            accI[h] += __shfl_xor(accI[h], m);
            accF[h] += __shfl_xor(accF[h], m);
        }
    }
    __shared__ float wsum[4][8];
    const int wave = t >> 6;
    if ((t & 63) == 0) {
        #pragma unroll
        for (int h = 0; h < 4; ++h) { wsum[wave][h] = accI[h]; wsum[wave][4 + h] = accF[h]; }
    }
    __syncthreads();
    if (t < 8) {
        float tot = wsum[0][t] + wsum[1][t] + wsum[2][t] + wsum[3][t];
        int h = t & 3;
        if (t < 4) ig_out[((size_t)(b * NH_ + h)) * S_ + s] = tot + igb[h];
        else       fg_out[((size_t)(b * NH_ + h)) * S_ + s] = tot + fgb[h];
    }
}

// ---------------- Kernel B: log-sigmoid cumsum + cummax scan ----------------
__global__ __launch_bounds__(256) void scan_kernel(
    const float* __restrict__ ig, const float* __restrict__ fg,
    float* __restrict__ AmM, float* __restrict__ G, float* __restrict__ M)
{
    const int bh = blockIdx.x;
    const int t = threadIdx.x;
    const float* fgp = fg + (size_t)bh * S_;
    const float* igp = ig + (size_t)bh * S_;
    float ls[8];
    float run = 0.f;
    #pragma unroll
    for (int i = 0; i < 8; ++i) {
        float x = fgp[t * 8 + i];
        float l = (x >= 0.f) ? -log1pf(expf(-x)) : (x - log1pf(expf(x)));
        run += l;
        ls[i] = run;
    }
    __shared__ float sc[256];
    sc[t] = run;
    __syncthreads();
    for (int off = 1; off < 256; off <<= 1) {
        float vv = (t >= off) ? sc[t - off] : 0.f;
        __syncthreads();
        sc[t] += vv;
        __syncthreads();
    }
    float excl = sc[t] - run;
    float A[8], g[8], gm[8];
    #pragma unroll
    for (int i = 0; i < 8; ++i) A[i] = excl + ls[i];
    float rmax = -__builtin_inff();
    #pragma unroll
    for (int i = 0; i < 8; ++i) {
        g[i] = igp[t * 8 + i] - A[i];
        rmax = fmaxf(rmax, g[i]);
        gm[i] = rmax;
    }
    __syncthreads();
    sc[t] = rmax;
    __syncthreads();
    for (int off = 1; off < 256; off <<= 1) {
        float vv = (t >= off) ? sc[t - off] : -__builtin_inff();
        __syncthreads();
        sc[t] = fmaxf(sc[t], vv);
        __syncthreads();
    }
    float exm = (t == 0) ? -__builtin_inff() : sc[t - 1];
    #pragma unroll
    for (int i = 0; i < 8; ++i) {
        float cm = fmaxf(exm, gm[i]);
        float Mi = A[i] + cm;
        size_t idx = (size_t)bh * S_ + t * 8 + i;
        AmM[idx] = A[i] - Mi;
        G[idx]   = g[i];
        M[idx]   = Mi;
    }
}

// ---------------- Kernel B2: V -> fp16 transposed [bh][HD][S] ----------------
__global__ __launch_bounds__(256) void transpose_v_kernel(
    const float* __restrict__ v, _Float16* __restrict__ Vt)
{
    const int bh = blockIdx.x, sb = blockIdx.y, db = blockIdx.z;
    const int b = bh >> 2, h = bh & 3;
    __shared__ float tile[64][65];
    const int t = threadIdx.x;
    const int j4 = (t & 15) * 4;
    const int i0 = t >> 4;
    const float* src = v + ((size_t)(b * S_ + sb * 64)) * E_ + h * HD_ + db * 64;
    #pragma unroll
    for (int p = 0; p < 4; ++p) {
        int i = i0 + p * 16;
        float4 val = *(const float4*)(src + (size_t)i * E_ + j4);
        tile[i][j4] = val.x; tile[i][j4+1] = val.y; tile[i][j4+2] = val.z; tile[i][j4+3] = val.w;
    }
    __syncthreads();
    const int s4 = (t & 15) * 4;
    const int d0 = t >> 4;
    _Float16* dst = Vt + ((size_t)bh * HD_ + db * 64) * S_ + sb * 64;
    #pragma unroll
    for (int p = 0; p < 4; ++p) {
        int d = d0 + p * 16;
        half4v pk;
        pk.x = (_Float16)tile[s4][d];   pk.y = (_Float16)tile[s4+1][d];
        pk.z = (_Float16)tile[s4+2][d]; pk.w = (_Float16)tile[s4+3][d];
        *(half4v*)(dst + (size_t)d * S_ + s4) = pk;
    }
}

// ---------------- Kernel C: MFMA causal decay attention + fused RMSNorm ----------------
// 256 blocks x 256 threads. Each wave owns one 16-row strip; strips paired
// {2u, 2u+1, 126-2u, 127-2u} for uniform causal work (130 tile-units/block).
__global__ __launch_bounds__(256, 1) void mlstm_mfma_kernel(
    const _Float16* __restrict__ Qh, const _Float16* __restrict__ Kh,
    const _Float16* __restrict__ Vt,
    const float* __restrict__ AmM, const float* __restrict__ G, const float* __restrict__ Mr,
    const float* __restrict__ rms_scale, float* __restrict__ out)
{
    __shared__ __align__(16) _Float16 Pls[4][16 * 40];  // per-wave P round-trip

    const int z  = blockIdx.x;
    const int bh = z >> 5;
    const int u  = z & 31;
    const int b  = bh >> 2, h = bh & 3;
    const int w  = threadIdx.x >> 6;
    const int l  = threadIdx.x & 63;
    const int col  = l & 15;
    const int quad = l >> 4;
    const int qo   = quad * 8;

    const int strip = (w < 2) ? (2 * u + w) : (126 - 2 * u + (w & 1));
    const int r0 = strip * 16;

    const _Float16* Qp = Qh + (size_t)bh * S_ * HD_;
    const _Float16* Kp = Kh + (size_t)bh * S_ * HD_;
    const _Float16* Vp = Vt + (size_t)bh * HD_ * S_;
    const float* AmMp = AmM + (size_t)bh * S_;
    const float* Gp   = G   + (size_t)bh * S_;
    const float* Mp   = Mr  + (size_t)bh * S_;

    // preload Q fragments (A-operand: m=col, k=qo+32*kk..)
    half8 qf[8];
    #pragma unroll
    for (int kk = 0; kk < 8; ++kk)
        qf[kk] = *(const half8*)(Qp + (size_t)(r0 + col) * HD_ + kk * 32 + qo);

    float amM[4], Mv[4];
    #pragma unroll
    for (int rr = 0; rr < 4; ++rr) {
        amM[rr] = AmMp[r0 + quad * 4 + rr];
        Mv[rr]  = Mp[r0 + quad * 4 + rr];
    }
    float rsc_v[16];
    #pragma unroll
    for (int nn = 0; nn < 16; ++nn) rsc_v[nn] = rms_scale[nn * 16 + col];

    f32x4 acc[16];
    #pragma unroll
    for (int nn = 0; nn < 16; ++nn) acc[nn] = (f32x4){0.f, 0.f, 0.f, 0.f};
    float rs[4] = {0.f, 0.f, 0.f, 0.f};

    half8 kf[16], vf[16];
    auto loadK = [&](int c0n) {
        #pragma unroll
        for (int t2 = 0; t2 < 2; ++t2)
            #pragma unroll
            for (int kk = 0; kk < 8; ++kk)
                kf[t2 * 8 + kk] = *(const half8*)(Kp + (size_t)(c0n + t2 * 16 + col) * HD_ + kk * 32 + qo);
    };
    auto loadV = [&](int c0n) {
        #pragma unroll
        for (int nn = 0; nn < 16; ++nn)
            vf[nn] = *(const half8*)(Vp + (size_t)(nn * 16 + col) * S_ + c0n + qo);
    };

    const int T = (r0 >> 5) + 1;
    loadK(0);
    loadV(0);

    _Float16* Pw = &Pls[w][0];

    for (int jt = 0; jt < T; ++jt) {
        const int c0 = jt << 5;
        const float gv0 = Gp[c0 + col];
        const float gv1 = Gp[c0 + 16 + col];

        f32x4 sc0 = (f32x4){0.f,0.f,0.f,0.f};
        f32x4 sc1 = (f32x4){0.f,0.f,0.f,0.f};
        #pragma unroll
        for (int kk = 0; kk < 8; ++kk) {
            sc0 = __builtin_amdgcn_mfma_f32_16x16x32_f16(qf[kk], kf[kk],     sc0, 0, 0, 0);
            sc1 = __builtin_amdgcn_mfma_f32_16x16x32_f16(qf[kk], kf[8 + kk], sc1, 0, 0, 0);
        }

        const int cn = (jt + 1 < T) ? (c0 + 32) : 0;
        loadK(cn);  // prefetch next K tile (kf's last use was above)

        // P fixup: p = s * exp(AmM[i]+G[j]) masked (select, not multiply: e may be inf)
        #pragma unroll
        for (int rr = 0; rr < 4; ++rr) {
            const int ig_ = r0 + quad * 4 + rr;
            float e0 = __expf(amM[rr] + gv0);
            float e1 = __expf(amM[rr] + gv1);
            float p0 = (c0 + col      <= ig_) ? sc0[rr] * e0 : 0.f;
            float p1 = (c0 + 16 + col <= ig_) ? sc1[rr] * e1 : 0.f;
            rs[rr] += p0 + p1;
            Pw[(quad * 4 + rr) * 40 + col]      = (_Float16)p0;
            Pw[(quad * 4 + rr) * 40 + 16 + col] = (_Float16)p1;
        }
        // A-operand read: P[m=col][k=qo..qo+7]  (wave-private, no barrier needed)
        half8 af = *(const half8*)(Pw + col * 40 + qo);

        #pragma unroll
        for (int nn = 0; nn < 16; ++nn)
            acc[nn] = __builtin_amdgcn_mfma_f32_16x16x32_f16(af, vf[nn], acc[nn], 0, 0, 0);

        loadV(cn);  // prefetch next V tile
    }

    // ---- epilogue: rowsum reduce, n, fused RMSNorm, store ----
    #pragma unroll
    for (int m = 1; m < 16; m <<= 1) {
        #pragma unroll
        for (int rr = 0; rr < 4; ++rr) rs[rr] += __shfl_xor(rs[rr], m);
    }
    float inv[4], ss[4];
    #pragma unroll
    for (int rr = 0; rr < 4; ++rr) {
        float n = fmaxf(rs[rr], __expf(-Mv[rr])) + 1e-6f;
        inv[rr] = 1.0f / n;
        ss[rr] = 0.f;
    }
    #pragma unroll
    for (int nn = 0; nn < 16; ++nn) {
        #pragma unroll
        for (int rr = 0; rr < 4; ++rr) {
            float hv = acc[nn][rr] * inv[rr];
            acc[nn][rr] = hv;
            ss[rr] = fmaf(hv, hv, ss[rr]);
        }
    }
    #pragma unroll
    for (int m = 1; m < 16; m <<= 1) {
        #pragma unroll
        for (int rr = 0; rr < 4; ++rr) ss[rr] += __shfl_xor(ss[rr], m);
    }
    float rstd[4];
    #pragma unroll
    for (int rr = 0; rr < 4; ++rr) rstd[rr] = rsqrtf(ss[rr] * (1.0f / HD_) + 1e-6f);

    #pragma unroll
    for (int rr = 0; rr < 4; ++rr) {
        float* orow = out + ((size_t)(b * S_ + r0 + quad * 4 + rr)) * E_ + h * HD_;
        #pragma unroll
        for (int nn = 0; nn < 16; ++nn)
            orow[nn * 16 + col] = acc[nn][rr] * rstd[rr] * (1.0f + rsc_v[nn]);
    }
}

extern "C" void kernel_launch(void* const* d_in, const int* in_sizes, int n_in,
                              void* d_out, int out_size, void* d_ws, size_t ws_size,
                              hipStream_t stream) {
    (void)in_sizes; (void)n_in; (void)out_size; (void)ws_size;
    const float* q   = (const float*)d_in[0];
    const float* k   = (const float*)d_in[1];
    const float* v   = (const float*)d_in[2];
    const float* igk = (const float*)d_in[3];
    const float* igb = (const float*)d_in[4];
    const float* fgk = (const float*)d_in[5];
    const float* fgb = (const float*)d_in[6];
    const float* rsc = (const float*)d_in[7];
    float* out = (float*)d_out;

    float* ws  = (float*)d_ws;
    float* ig  = ws;                          // BH*S each
    float* fg  = ws + (size_t)BH_ * S_;
    float* AmM = ws + (size_t)2 * BH_ * S_;
    float* G   = ws + (size_t)3 * BH_ * S_;
    float* M   = ws + (size_t)4 * BH_ * S_;
    _Float16* Qh = (_Float16*)(ws + (size_t)5 * BH_ * S_);
    _Float16* Kh = Qh + (size_t)BH_ * S_ * HD_;
    _Float16* Vt = Kh + (size_t)BH_ * S_ * HD_;

    gates_kernel<<<B_ * S_, 256, 0, stream>>>(q, k, v, igk, igb, fgk, fgb, ig, fg, Qh, Kh);
    scan_kernel<<<BH_, 256, 0, stream>>>(ig, fg, AmM, G, M);
    dim3 tg(BH_, S_ / 64, HD_ / 64);
    transpose_v_kernel<<<tg, 256, 0, stream>>>(v, Vt);
    mlstm_mfma_kernel<<<BH_ * 32, 256, 0, stream>>>(Qh, Kh, Vt, AmM, G, M, rsc, out);
}